// Round 1
// baseline (457.141 us; speedup 1.0000x reference)
//
#include <hip/hip_runtime.h>

#define DIN   128
#define DSL   64
#define KSL   11
#define NTOK  4096
#define NB    64
#define NSPLIT 32
#define ROWS_PER_SPLIT 128   // 4096/32
#define LN_EPS   1e-5f
#define ATTN_EPS 1e-8f
#define SCALE    0.125f      // 64^-0.5

// ---------------------------------------------------------------------------
// Kernel 1: fused LayerNorm(inputs) @ Wk / @ Wv  -> keys, vals  [B,N,64]
// Wave processes 8 rows per pass; weights interleaved in LDS (one b64 read
// feeds both Wk and Wv FMAs); xn broadcast as float4. FMA-bound by design.
// ---------------------------------------------------------------------------
__launch_bounds__(256, 2)
__global__ void k_lnproj(const float* __restrict__ inp, const float* __restrict__ g,
                         const float* __restrict__ bb, const float* __restrict__ Wk,
                         const float* __restrict__ Wv, float* __restrict__ keys,
                         float* __restrict__ vals) {
  __shared__ __align__(16) float wi[DIN][2 * DSL];   // 64 KB: wi[i][2c]=Wk[i][c], [2c+1]=Wv[i][c]
  __shared__ __align__(16) float xn[4][8][DIN];      // 16 KB: per-wave normalized rows
  const int tid = threadIdx.x;
  const int wave = tid >> 6, lane = tid & 63;

  for (int idx = tid; idx < DIN * DSL; idx += 256) {
    const int i = idx >> 6, c = idx & 63;
    wi[i][2 * c]     = Wk[idx];
    wi[i][2 * c + 1] = Wv[idx];
  }
  const float g0 = g[2 * lane], g1 = g[2 * lane + 1];
  const float b0 = bb[2 * lane], b1 = bb[2 * lane + 1];
  __syncthreads();

  for (int it = 0; it < 8; ++it) {
    const int row0 = (it * 1024 + blockIdx.x) * 32 + wave * 8;   // grid must be 1024
    float nx0[8], nx1[8];
#pragma unroll
    for (int r = 0; r < 8; ++r) {
      const float2 v = *(const float2*)(inp + (size_t)(row0 + r) * DIN + 2 * lane);
      float s = v.x + v.y, sq = v.x * v.x + v.y * v.y;
#pragma unroll
      for (int o = 32; o > 0; o >>= 1) { s += __shfl_xor(s, o); sq += __shfl_xor(sq, o); }
      const float m = s * (1.f / 128.f);
      const float var = sq * (1.f / 128.f) - m * m;
      const float rstd = rsqrtf(var + LN_EPS);
      nx0[r] = (v.x - m) * rstd * g0 + b0;
      nx1[r] = (v.y - m) * rstd * g1 + b1;
    }
#pragma unroll
    for (int r = 0; r < 8; ++r)
      *(float2*)&xn[wave][r][2 * lane] = make_float2(nx0[r], nx1[r]);
    __syncthreads();

    float ak[8] = {0.f, 0.f, 0.f, 0.f, 0.f, 0.f, 0.f, 0.f};
    float av[8] = {0.f, 0.f, 0.f, 0.f, 0.f, 0.f, 0.f, 0.f};
#pragma unroll 4
    for (int i4 = 0; i4 < 32; ++i4) {
      const float2 w0 = *(const float2*)&wi[4 * i4 + 0][2 * lane];
      const float2 w1 = *(const float2*)&wi[4 * i4 + 1][2 * lane];
      const float2 w2 = *(const float2*)&wi[4 * i4 + 2][2 * lane];
      const float2 w3 = *(const float2*)&wi[4 * i4 + 3][2 * lane];
#pragma unroll
      for (int r = 0; r < 8; ++r) {
        const float4 xv = *(const float4*)&xn[wave][r][4 * i4];
        ak[r] += xv.x * w0.x + xv.y * w1.x + xv.z * w2.x + xv.w * w3.x;
        av[r] += xv.x * w0.y + xv.y * w1.y + xv.z * w2.y + xv.w * w3.y;
      }
    }
#pragma unroll
    for (int r = 0; r < 8; ++r) {
      keys[(size_t)(row0 + r) * DSL + lane] = ak[r];
      vals[(size_t)(row0 + r) * DSL + lane] = av[r];
    }
    __syncthreads();
  }
}

// ---------------------------------------------------------------------------
// Kernel 2: slots = broadcast(init_latents); q = LN_q(slots) @ Wq
// Block = 704 threads = 11 waves (wave = slot k, lane = channel c).
// ---------------------------------------------------------------------------
__global__ void k_init(const float* __restrict__ init_lat, const float* __restrict__ qg,
                       const float* __restrict__ qb, const float* __restrict__ Wq,
                       float* __restrict__ slots, float* __restrict__ q) {
  const int b = blockIdx.x;
  const int k = threadIdx.x >> 6, c = threadIdx.x & 63;
  const float s = init_lat[k * DSL + c];
  slots[(size_t)(b * KSL + k) * DSL + c] = s;
  float sum = s, sq = s * s;
#pragma unroll
  for (int o = 32; o > 0; o >>= 1) { sum += __shfl_xor(sum, o); sq += __shfl_xor(sq, o); }
  const float m = sum * (1.f / 64.f);
  const float rstd = rsqrtf(sq * (1.f / 64.f) - m * m + LN_EPS);
  const float qn = (s - m) * rstd * qg[c] + qb[c];
  float acc = 0.f;
  for (int i = 0; i < DSL; ++i) acc += __shfl(qn, i) * Wq[i * DSL + c];
  q[(size_t)(b * KSL + k) * DSL + c] = acc;
}

// ---------------------------------------------------------------------------
// Kernel 3: attention pass. One wave per block; 128 rows per block (2 tiles
// of 64). Per tile: stage keys -> LDS (pad 65, conflict-free transposed
// reads), logits via wave-uniform scalar q loads, lane-local softmax over
// K=11, accumulate S[m] (lane-partial, reduced once at end) and U[m][c]
// (lane = c, attn broadcast from LDS). Deterministic split-K partials.
// ---------------------------------------------------------------------------
__launch_bounds__(64)
__global__ void k_attn(const float* __restrict__ keys, const float* __restrict__ vals,
                       const float* __restrict__ q, float* __restrict__ Upart,
                       float* __restrict__ Spart, float* __restrict__ attn_out) {
  __shared__ __align__(16) float tile[64 * 65];
  __shared__ __align__(16) float at[64 * 12];
  const int b = blockIdx.x >> 5, sp = blockIdx.x & 31;
  const int lane = threadIdx.x;
  const float* __restrict__ qb = q + (size_t)b * (KSL * DSL);
  const size_t base = ((size_t)b * NTOK + sp * ROWS_PER_SPLIT) * DSL;

  float U[KSL] = {0.f, 0.f, 0.f, 0.f, 0.f, 0.f, 0.f, 0.f, 0.f, 0.f, 0.f};
  float Sl[KSL] = {0.f, 0.f, 0.f, 0.f, 0.f, 0.f, 0.f, 0.f, 0.f, 0.f, 0.f};

  for (int t = 0; t < 2; ++t) {
    const int nt = t * 64;
    {  // stage 64x64 keys tile
      const int row = lane >> 4, c4 = (lane & 15) * 4;
#pragma unroll
      for (int p = 0; p < 16; ++p) {
        const float4 kv = *(const float4*)(keys + base + (size_t)(nt + p * 4 + row) * DSL + c4);
        float* d = &tile[(p * 4 + row) * 65 + c4];
        d[0] = kv.x; d[1] = kv.y; d[2] = kv.z; d[3] = kv.w;
      }
    }
    __syncthreads();

    float lg[KSL] = {0.f, 0.f, 0.f, 0.f, 0.f, 0.f, 0.f, 0.f, 0.f, 0.f, 0.f};
    for (int c = 0; c < DSL; ++c) {
      const float kv = tile[lane * 65 + c];
#pragma unroll
      for (int m = 0; m < KSL; ++m) lg[m] += kv * qb[m * DSL + c];
    }
#pragma unroll
    for (int m = 0; m < KSL; ++m) lg[m] *= SCALE;
    float mx = lg[0];
#pragma unroll
    for (int m = 1; m < KSL; ++m) mx = fmaxf(mx, lg[m]);
    float e[KSL]; float se = 0.f;
#pragma unroll
    for (int m = 0; m < KSL; ++m) { e[m] = __expf(lg[m] - mx); se += e[m]; }
    const float inv = 1.f / se;
    float a[KSL];
#pragma unroll
    for (int m = 0; m < KSL; ++m) {
      a[m] = e[m] * inv + ATTN_EPS;
      Sl[m] += a[m];
      at[lane * 12 + m] = a[m];
    }
    if (attn_out) {
      float* ao = attn_out + ((size_t)b * NTOK + sp * ROWS_PER_SPLIT + nt + lane) * KSL;
#pragma unroll
      for (int m = 0; m < KSL; ++m) ao[m] = a[m];
    }
    __syncthreads();

#pragma unroll 4
    for (int n = 0; n < 64; ++n) {
      const float4 a0 = *(const float4*)&at[n * 12 + 0];
      const float4 a1 = *(const float4*)&at[n * 12 + 4];
      const float4 a2 = *(const float4*)&at[n * 12 + 8];
      const float v = vals[base + (size_t)(nt + n) * DSL + lane];
      U[0] += a0.x * v; U[1] += a0.y * v; U[2]  += a0.z * v; U[3] += a0.w * v;
      U[4] += a1.x * v; U[5] += a1.y * v; U[6]  += a1.z * v; U[7] += a1.w * v;
      U[8] += a2.x * v; U[9] += a2.y * v; U[10] += a2.z * v;
    }
    __syncthreads();
  }

  float* up = Upart + (size_t)(b * NSPLIT + sp) * KSL * DSL;
#pragma unroll
  for (int m = 0; m < KSL; ++m) up[m * DSL + lane] = U[m];
#pragma unroll
  for (int m = 0; m < KSL; ++m) {
#pragma unroll
    for (int o = 32; o > 0; o >>= 1) Sl[m] += __shfl_xor(Sl[m], o);
  }
  if (lane == 0) {
    float* spp = Spart + (size_t)(b * NSPLIT + sp) * KSL;
#pragma unroll
    for (int m = 0; m < KSL; ++m) spp[m] = Sl[m];
  }
}

// ---------------------------------------------------------------------------
// Kernel 4: reduce partials -> updates; GRU cell; LN_f + MLP residual;
// write slots (and d_out on last iter); compute q for next iter.
// Block = 704 threads = 11 waves (wave = slot k, lane = channel c).
// ---------------------------------------------------------------------------
__global__ void k_update(const float* __restrict__ Upart, const float* __restrict__ Spart,
                         float* __restrict__ slots, const float* __restrict__ w_ih,
                         const float* __restrict__ w_hh, const float* __restrict__ b_ih,
                         const float* __restrict__ b_hh, const float* __restrict__ fg,
                         const float* __restrict__ fb, const float* __restrict__ W1,
                         const float* __restrict__ b1v, const float* __restrict__ W2,
                         const float* __restrict__ b2v, const float* __restrict__ qg,
                         const float* __restrict__ qbv, const float* __restrict__ Wq,
                         float* __restrict__ q, float* __restrict__ out_slots) {
  const int b = blockIdx.x;
  const int k = threadIdx.x >> 6, c = threadIdx.x & 63;

  float u = 0.f;
  for (int s = 0; s < NSPLIT; ++s)
    u += Upart[((size_t)(b * NSPLIT + s) * KSL + k) * DSL + c];
  float ss = 0.f;
  for (int s = 0; s < NSPLIT; ++s)
    ss += Spart[(size_t)(b * NSPLIT + s) * KSL + k];
  u /= ss;

  const int row = b * KSL + k;
  const float h = slots[(size_t)row * DSL + c];

  float gr = b_ih[c], gz = b_ih[64 + c], gn = b_ih[128 + c];
  float hr = b_hh[c], hz = b_hh[64 + c], hn = b_hh[128 + c];
  for (int i = 0; i < 64; ++i) {
    const float ui = __shfl(u, i), hi = __shfl(h, i);
    gr += ui * w_ih[i * 192 + c];       hr += hi * w_hh[i * 192 + c];
    gz += ui * w_ih[i * 192 + 64 + c];  hz += hi * w_hh[i * 192 + 64 + c];
    gn += ui * w_ih[i * 192 + 128 + c]; hn += hi * w_hh[i * 192 + 128 + c];
  }
  const float r = 1.f / (1.f + __expf(-(gr + hr)));
  const float z = 1.f / (1.f + __expf(-(gz + hz)));
  const float nn = tanhf(gn + r * hn);
  float sv = (1.f - z) * nn + z * h;

  // LN_f
  float sum = sv, sq = sv * sv;
#pragma unroll
  for (int o = 32; o > 0; o >>= 1) { sum += __shfl_xor(sum, o); sq += __shfl_xor(sq, o); }
  float m = sum * (1.f / 64.f);
  float rstd = rsqrtf(sq * (1.f / 64.f) - m * m + LN_EPS);
  const float sl = (sv - m) * rstd * fg[c] + fb[c];

  float h0 = b1v[c], h1 = b1v[64 + c], h2 = b1v[128 + c], h3 = b1v[192 + c];
  for (int i = 0; i < 64; ++i) {
    const float si = __shfl(sl, i);
    h0 += si * W1[i * 256 + c];        h1 += si * W1[i * 256 + 64 + c];
    h2 += si * W1[i * 256 + 128 + c];  h3 += si * W1[i * 256 + 192 + c];
  }
  h0 = fmaxf(h0, 0.f); h1 = fmaxf(h1, 0.f); h2 = fmaxf(h2, 0.f); h3 = fmaxf(h3, 0.f);

  float o = b2v[c];
  for (int j = 0; j < 64; ++j) o += __shfl(h0, j) * W2[j * DSL + c];
  for (int j = 0; j < 64; ++j) o += __shfl(h1, j) * W2[(64 + j) * DSL + c];
  for (int j = 0; j < 64; ++j) o += __shfl(h2, j) * W2[(128 + j) * DSL + c];
  for (int j = 0; j < 64; ++j) o += __shfl(h3, j) * W2[(192 + j) * DSL + c];
  sv += o;

  slots[(size_t)row * DSL + c] = sv;
  if (out_slots) out_slots[(size_t)row * DSL + c] = sv;

  // q for next iteration
  float s2 = sv, q2 = sv * sv;
#pragma unroll
  for (int o2 = 32; o2 > 0; o2 >>= 1) { s2 += __shfl_xor(s2, o2); q2 += __shfl_xor(q2, o2); }
  m = s2 * (1.f / 64.f);
  rstd = rsqrtf(q2 * (1.f / 64.f) - m * m + LN_EPS);
  const float qn = (sv - m) * rstd * qg[c] + qbv[c];
  float qa = 0.f;
  for (int i = 0; i < 64; ++i) qa += __shfl(qn, i) * Wq[i * DSL + c];
  q[(size_t)row * DSL + c] = qa;
}

// ---------------------------------------------------------------------------
extern "C" void kernel_launch(void* const* d_in, const int* in_sizes, int n_in,
                              void* d_out, int out_size, void* d_ws, size_t ws_size,
                              hipStream_t stream) {
  const float* inp  = (const float*)d_in[0];
  const float* lng  = (const float*)d_in[1];
  const float* lnb  = (const float*)d_in[2];
  const float* Wk   = (const float*)d_in[3];
  const float* Wv   = (const float*)d_in[4];
  const float* init = (const float*)d_in[5];
  const float* qg   = (const float*)d_in[6];
  const float* qbb  = (const float*)d_in[7];
  const float* Wq   = (const float*)d_in[8];
  const float* wih  = (const float*)d_in[9];
  const float* whh  = (const float*)d_in[10];
  const float* bih  = (const float*)d_in[11];
  const float* bhh  = (const float*)d_in[12];
  const float* fg   = (const float*)d_in[13];
  const float* fb   = (const float*)d_in[14];
  const float* W1   = (const float*)d_in[15];
  const float* b1   = (const float*)d_in[16];
  const float* W2   = (const float*)d_in[17];
  const float* b2   = (const float*)d_in[18];

  float* ws    = (float*)d_ws;
  float* keys  = ws;
  float* vals  = keys + (size_t)NB * NTOK * DSL;
  float* slots = vals + (size_t)NB * NTOK * DSL;
  float* q     = slots + NB * KSL * DSL;
  float* Upart = q + NB * KSL * DSL;
  float* Spart = Upart + (size_t)NB * NSPLIT * KSL * DSL;

  float* out_slots = (float*)d_out;
  float* out_attn  = (float*)d_out + NB * KSL * DSL;

  k_lnproj<<<1024, 256, 0, stream>>>(inp, lng, lnb, Wk, Wv, keys, vals);
  k_init<<<NB, KSL * 64, 0, stream>>>(init, qg, qbb, Wq, slots, q);
  for (int t = 0; t < 3; ++t) {
    k_attn<<<NB * NSPLIT, 64, 0, stream>>>(keys, vals, q, Upart, Spart,
                                           t == 2 ? out_attn : nullptr);
    k_update<<<NB, KSL * 64, 0, stream>>>(Upart, Spart, slots, wih, whh, bih, bhh,
                                          fg, fb, W1, b1, W2, b2, qg, qbb, Wq, q,
                                          t == 2 ? out_slots : nullptr);
  }
}

// Round 2
// 228.085 us; speedup vs baseline: 2.0043x; 2.0043x over previous
//
#include <hip/hip_runtime.h>

#define DIN   128
#define DSL   64
#define KSL   11
#define NTOK  4096
#define NB    64
#define NSPLIT 64
#define LN_EPS   1e-5f
#define ATTN_EPS 1e-8f
#define SCALE    0.125f      // 64^-0.5

typedef __bf16 bf16x8 __attribute__((ext_vector_type(8)));
typedef float  f32x4  __attribute__((ext_vector_type(4)));

// ---------------------------------------------------------------------------
// Kernel 0: pre-gather Wk|Wv (f32 [128][64] each) into MFMA b-fragment order:
// WTf[(ks*8+nt)*64 + lane] holds 8 bf16 = B[k = ks*32+(lane>>4)*8 + j][col =
// nt*16+(lane&15)], j=0..7.  k_lnproj then loads B-frags fully coalesced.
// ---------------------------------------------------------------------------
__global__ void k_prep(const float* __restrict__ Wk, const float* __restrict__ Wv,
                       __bf16* __restrict__ WTf) {
  const int t = blockIdx.x * 256 + threadIdx.x;   // 0..2047
  const int fid = t >> 6, lane = t & 63;          // fid = ks*8+nt
  const int ks = fid >> 3, nt = fid & 7;
  const int col = nt * 16 + (lane & 15);
  const int kb  = ks * 32 + (lane >> 4) * 8;
  union { uint4 u; __bf16 h[8]; } o;
#pragma unroll
  for (int j = 0; j < 8; ++j) {
    const int k = kb + j;
    const float v = (col < 64) ? Wk[k * 64 + col] : Wv[k * 64 + (col - 64)];
    o.h[j] = (__bf16)v;
  }
  *((uint4*)WTf + t) = o.u;
}

// ---------------------------------------------------------------------------
// Kernel 1: fused LayerNorm(inputs) + bf16 MFMA projection -> keys, vals (bf16)
// 4096 blocks x 256 thr; wave = 16-row stripe; no __syncthreads (per-wave LDS).
// ---------------------------------------------------------------------------
__launch_bounds__(256)
__global__ void k_lnproj(const float* __restrict__ inp, const float* __restrict__ g,
                         const float* __restrict__ bb, const __bf16* __restrict__ WTf,
                         __bf16* __restrict__ keys, __bf16* __restrict__ vals) {
  __shared__ __bf16 Xs[4][16][136];   // pad 8 bf16 -> row stride 272B (2-way max)
  const int tid = threadIdx.x, wave = tid >> 6, lane = tid & 63;
  const int half = lane >> 5, hl = lane & 31;
  const int rbase = blockIdx.x * 64 + wave * 16;

  const float4 gv = *(const float4*)(g + hl * 4);
  const float4 bv = *(const float4*)(bb + hl * 4);

#pragma unroll
  for (int p = 0; p < 8; ++p) {
    const int row = p * 2 + half;
    const float4 x = *(const float4*)(inp + (size_t)(rbase + row) * DIN + hl * 4);
    float s  = x.x + x.y + x.z + x.w;
    float sq = x.x * x.x + x.y * x.y + x.z * x.z + x.w * x.w;
#pragma unroll
    for (int o = 16; o > 0; o >>= 1) { s += __shfl_xor(s, o); sq += __shfl_xor(sq, o); }
    const float m = s * (1.f / 128.f);
    const float rstd = rsqrtf(sq * (1.f / 128.f) - m * m + LN_EPS);
    union { ushort4 u; __bf16 h[4]; } pk;
    pk.h[0] = (__bf16)((x.x - m) * rstd * gv.x + bv.x);
    pk.h[1] = (__bf16)((x.y - m) * rstd * gv.y + bv.y);
    pk.h[2] = (__bf16)((x.z - m) * rstd * gv.z + bv.z);
    pk.h[3] = (__bf16)((x.w - m) * rstd * gv.w + bv.w);
    *(ushort4*)&Xs[wave][row][hl * 4] = pk.u;
  }
  // No barrier: each wave reads only its own Xs[wave] slice.

  f32x4 acc[8] = {};
  const int arow = lane & 15, kgrp = lane >> 4;
  const bf16x8* __restrict__ Bv = (const bf16x8*)WTf;
#pragma unroll
  for (int ks = 0; ks < 4; ++ks) {
    const bf16x8 a = *(const bf16x8*)&Xs[wave][arow][ks * 32 + kgrp * 8];
#pragma unroll
    for (int nt = 0; nt < 8; ++nt) {
      const bf16x8 b = Bv[(ks * 8 + nt) * 64 + lane];
      acc[nt] = __builtin_amdgcn_mfma_f32_16x16x32_bf16(a, b, acc[nt], 0, 0, 0);
    }
  }
  // C/D layout: col = lane&15, row = (lane>>4)*4 + reg  [m89-verified]
#pragma unroll
  for (int nt = 0; nt < 8; ++nt) {
    __bf16* __restrict__ dst = (nt < 4) ? keys : vals;
    const int c = (nt & 3) * 16 + arow;
#pragma unroll
    for (int r = 0; r < 4; ++r)
      dst[(size_t)(rbase + kgrp * 4 + r) * DSL + c] = (__bf16)acc[nt][r];
  }
}

// ---------------------------------------------------------------------------
// Kernel 2: slots = broadcast(init_latents); q = LN_q(slots) @ Wq
// ---------------------------------------------------------------------------
__global__ void k_init(const float* __restrict__ init_lat, const float* __restrict__ qg,
                       const float* __restrict__ qb, const float* __restrict__ Wq,
                       float* __restrict__ slots, float* __restrict__ q) {
  const int b = blockIdx.x;
  const int k = threadIdx.x >> 6, c = threadIdx.x & 63;
  const float s = init_lat[k * DSL + c];
  slots[(size_t)(b * KSL + k) * DSL + c] = s;
  float sum = s, sq = s * s;
#pragma unroll
  for (int o = 32; o > 0; o >>= 1) { sum += __shfl_xor(sum, o); sq += __shfl_xor(sq, o); }
  const float m = sum * (1.f / 64.f);
  const float rstd = rsqrtf(sq * (1.f / 64.f) - m * m + LN_EPS);
  const float qn = (s - m) * rstd * qg[c] + qb[c];
  float acc = 0.f;
  for (int i = 0; i < DSL; ++i) acc += __shfl(qn, i) * Wq[i * DSL + c];
  q[(size_t)(b * KSL + k) * DSL + c] = acc;
}

// ---------------------------------------------------------------------------
// Kernel 3: attention pass (bf16 keys/vals). One wave per 64-row tile.
// Key row in registers; logits via bit-trick bf16->f32; softmax lane-local
// over K=11; PV with broadcast attn from LDS. Deterministic split partials.
// ---------------------------------------------------------------------------
__launch_bounds__(64)
__global__ void k_attn(const __bf16* __restrict__ keys, const __bf16* __restrict__ vals,
                       const float* __restrict__ q, float* __restrict__ Upart,
                       float* __restrict__ Spart, float* __restrict__ attn_out) {
  __shared__ __align__(16) float at[64 * 12];
  const int b = blockIdx.x >> 6, sp = blockIdx.x & 63;
  const int lane = threadIdx.x;
  const float* __restrict__ qbp = q + b * (KSL * DSL);
  const size_t base = ((size_t)b * NTOK + sp * 64) * DSL;

  unsigned int kw[32];
  {
    const uint4* __restrict__ kp = (const uint4*)(keys + base + (size_t)lane * DSL);
#pragma unroll
    for (int i = 0; i < 8; ++i) {
      const uint4 t = kp[i];
      kw[4 * i] = t.x; kw[4 * i + 1] = t.y; kw[4 * i + 2] = t.z; kw[4 * i + 3] = t.w;
    }
  }
  float lg[KSL] = {0.f, 0.f, 0.f, 0.f, 0.f, 0.f, 0.f, 0.f, 0.f, 0.f, 0.f};
#pragma unroll
  for (int c2 = 0; c2 < 32; ++c2) {
    const float lo = __uint_as_float(kw[c2] << 16);
    const float hi = __uint_as_float(kw[c2] & 0xffff0000u);
#pragma unroll
    for (int m = 0; m < KSL; ++m)
      lg[m] = fmaf(hi, qbp[m * DSL + 2 * c2 + 1], fmaf(lo, qbp[m * DSL + 2 * c2], lg[m]));
  }
  float mx = lg[0] * SCALE;
#pragma unroll
  for (int m = 0; m < KSL; ++m) { lg[m] *= SCALE; mx = fmaxf(mx, lg[m]); }
  float e[KSL], se = 0.f;
#pragma unroll
  for (int m = 0; m < KSL; ++m) { e[m] = __expf(lg[m] - mx); se += e[m]; }
  const float inv = 1.f / se;
  float a[KSL];
#pragma unroll
  for (int m = 0; m < KSL; ++m) {
    a[m] = e[m] * inv + ATTN_EPS;
    at[lane * 12 + m] = a[m];
  }
  if (attn_out) {
    float* __restrict__ ao = attn_out + ((size_t)b * NTOK + sp * 64 + lane) * KSL;
#pragma unroll
    for (int m = 0; m < KSL; ++m) ao[m] = a[m];
  }
  __syncthreads();

  float U[KSL] = {0.f, 0.f, 0.f, 0.f, 0.f, 0.f, 0.f, 0.f, 0.f, 0.f, 0.f};
#pragma unroll 8
  for (int n = 0; n < 64; ++n) {
    const unsigned short us = *(const unsigned short*)(vals + base + (size_t)n * DSL + lane);
    const float v = __uint_as_float(((unsigned int)us) << 16);
    const float4 a0 = *(const float4*)&at[n * 12 + 0];
    const float4 a1 = *(const float4*)&at[n * 12 + 4];
    const float4 a2 = *(const float4*)&at[n * 12 + 8];
    U[0] += a0.x * v; U[1] += a0.y * v; U[2]  += a0.z * v; U[3] += a0.w * v;
    U[4] += a1.x * v; U[5] += a1.y * v; U[6]  += a1.z * v; U[7] += a1.w * v;
    U[8] += a2.x * v; U[9] += a2.y * v; U[10] += a2.z * v;
  }
  float* __restrict__ up = Upart + (size_t)(b * NSPLIT + sp) * (KSL * DSL);
#pragma unroll
  for (int m = 0; m < KSL; ++m) up[m * DSL + lane] = U[m];
  float Sl[KSL];
#pragma unroll
  for (int m = 0; m < KSL; ++m) {
    Sl[m] = a[m];
#pragma unroll
    for (int o = 32; o > 0; o >>= 1) Sl[m] += __shfl_xor(Sl[m], o);
  }
  if (lane == 0) {
    float* __restrict__ spp = Spart + (size_t)(b * NSPLIT + sp) * KSL;
#pragma unroll
    for (int m = 0; m < KSL; ++m) spp[m] = Sl[m];
  }
}

// ---------------------------------------------------------------------------
// Kernel 4: reduce partials -> updates; GRU; LN_f + MLP residual; next q.
// ---------------------------------------------------------------------------
__global__ void k_update(const float* __restrict__ Upart, const float* __restrict__ Spart,
                         float* __restrict__ slots, const float* __restrict__ w_ih,
                         const float* __restrict__ w_hh, const float* __restrict__ b_ih,
                         const float* __restrict__ b_hh, const float* __restrict__ fg,
                         const float* __restrict__ fb, const float* __restrict__ W1,
                         const float* __restrict__ b1v, const float* __restrict__ W2,
                         const float* __restrict__ b2v, const float* __restrict__ qg,
                         const float* __restrict__ qbv, const float* __restrict__ Wq,
                         float* __restrict__ q, float* __restrict__ out_slots) {
  const int b = blockIdx.x;
  const int k = threadIdx.x >> 6, c = threadIdx.x & 63;

  float u = 0.f;
  for (int s = 0; s < NSPLIT; ++s)
    u += Upart[((size_t)(b * NSPLIT + s) * KSL + k) * DSL + c];
  float ss = 0.f;
  for (int s = 0; s < NSPLIT; ++s)
    ss += Spart[(size_t)(b * NSPLIT + s) * KSL + k];
  u /= ss;

  const int row = b * KSL + k;
  const float h = slots[(size_t)row * DSL + c];

  float gr = b_ih[c], gz = b_ih[64 + c], gn = b_ih[128 + c];
  float hr = b_hh[c], hz = b_hh[64 + c], hn = b_hh[128 + c];
  for (int i = 0; i < 64; ++i) {
    const float ui = __shfl(u, i), hi = __shfl(h, i);
    gr += ui * w_ih[i * 192 + c];       hr += hi * w_hh[i * 192 + c];
    gz += ui * w_ih[i * 192 + 64 + c];  hz += hi * w_hh[i * 192 + 64 + c];
    gn += ui * w_ih[i * 192 + 128 + c]; hn += hi * w_hh[i * 192 + 128 + c];
  }
  const float r = 1.f / (1.f + __expf(-(gr + hr)));
  const float z = 1.f / (1.f + __expf(-(gz + hz)));
  const float nn = tanhf(gn + r * hn);
  float sv = (1.f - z) * nn + z * h;

  float sum = sv, sq = sv * sv;
#pragma unroll
  for (int o = 32; o > 0; o >>= 1) { sum += __shfl_xor(sum, o); sq += __shfl_xor(sq, o); }
  float m = sum * (1.f / 64.f);
  float rstd = rsqrtf(sq * (1.f / 64.f) - m * m + LN_EPS);
  const float sl = (sv - m) * rstd * fg[c] + fb[c];

  float h0 = b1v[c], h1 = b1v[64 + c], h2 = b1v[128 + c], h3 = b1v[192 + c];
  for (int i = 0; i < 64; ++i) {
    const float si = __shfl(sl, i);
    h0 += si * W1[i * 256 + c];        h1 += si * W1[i * 256 + 64 + c];
    h2 += si * W1[i * 256 + 128 + c];  h3 += si * W1[i * 256 + 192 + c];
  }
  h0 = fmaxf(h0, 0.f); h1 = fmaxf(h1, 0.f); h2 = fmaxf(h2, 0.f); h3 = fmaxf(h3, 0.f);

  float o = b2v[c];
  for (int j = 0; j < 64; ++j) o += __shfl(h0, j) * W2[j * DSL + c];
  for (int j = 0; j < 64; ++j) o += __shfl(h1, j) * W2[(64 + j) * DSL + c];
  for (int j = 0; j < 64; ++j) o += __shfl(h2, j) * W2[(128 + j) * DSL + c];
  for (int j = 0; j < 64; ++j) o += __shfl(h3, j) * W2[(192 + j) * DSL + c];
  sv += o;

  slots[(size_t)row * DSL + c] = sv;
  if (out_slots) out_slots[(size_t)row * DSL + c] = sv;

  float s2 = sv, q2 = sv * sv;
#pragma unroll
  for (int o2 = 32; o2 > 0; o2 >>= 1) { s2 += __shfl_xor(s2, o2); q2 += __shfl_xor(q2, o2); }
  m = s2 * (1.f / 64.f);
  rstd = rsqrtf(q2 * (1.f / 64.f) - m * m + LN_EPS);
  const float qn = (sv - m) * rstd * qg[c] + qbv[c];
  float qa = 0.f;
  for (int i = 0; i < 64; ++i) qa += __shfl(qn, i) * Wq[i * DSL + c];
  q[(size_t)row * DSL + c] = qa;
}

// ---------------------------------------------------------------------------
extern "C" void kernel_launch(void* const* d_in, const int* in_sizes, int n_in,
                              void* d_out, int out_size, void* d_ws, size_t ws_size,
                              hipStream_t stream) {
  const float* inp  = (const float*)d_in[0];
  const float* lng  = (const float*)d_in[1];
  const float* lnb  = (const float*)d_in[2];
  const float* Wk   = (const float*)d_in[3];
  const float* Wv   = (const float*)d_in[4];
  const float* init = (const float*)d_in[5];
  const float* qg   = (const float*)d_in[6];
  const float* qbb  = (const float*)d_in[7];
  const float* Wq   = (const float*)d_in[8];
  const float* wih  = (const float*)d_in[9];
  const float* whh  = (const float*)d_in[10];
  const float* bih  = (const float*)d_in[11];
  const float* bhh  = (const float*)d_in[12];
  const float* fg   = (const float*)d_in[13];
  const float* fb   = (const float*)d_in[14];
  const float* W1   = (const float*)d_in[15];
  const float* b1   = (const float*)d_in[16];
  const float* W2   = (const float*)d_in[17];
  const float* b2   = (const float*)d_in[18];

  char* wsb = (char*)d_ws;
  __bf16* keys = (__bf16*)wsb;                                   // 33.55 MB
  __bf16* vals = keys + (size_t)NB * NTOK * DSL;                 // 33.55 MB
  __bf16* WTf  = vals + (size_t)NB * NTOK * DSL;                 // 32 KB
  float* slots = (float*)(WTf + 16384);
  float* q     = slots + NB * KSL * DSL;
  float* Upart = q + NB * KSL * DSL;
  float* Spart = Upart + (size_t)NB * NSPLIT * KSL * DSL;        // 11.5 MB

  float* out_slots = (float*)d_out;
  float* out_attn  = (float*)d_out + NB * KSL * DSL;

  k_prep<<<8, 256, 0, stream>>>(Wk, Wv, WTf);
  k_lnproj<<<4096, 256, 0, stream>>>(inp, lng, lnb, WTf, keys, vals);
  k_init<<<NB, KSL * 64, 0, stream>>>(init, qg, qbb, Wq, slots, q);
  for (int t = 0; t < 3; ++t) {
    k_attn<<<NB * NSPLIT, 64, 0, stream>>>(keys, vals, q, Upart, Spart,
                                           t == 2 ? out_attn : nullptr);
    k_update<<<NB, KSL * 64, 0, stream>>>(Upart, Spart, slots, wih, whh, bih, bhh,
                                          fg, fb, W1, b1, W2, b2, qg, qbb, Wq, q,
                                          t == 2 ? out_slots : nullptr);
  }
}

// Round 3
// 222.592 us; speedup vs baseline: 2.0537x; 1.0247x over previous
//
#include <hip/hip_runtime.h>

#define DIN   128
#define DSL   64
#define KSL   11
#define NTOK  4096
#define NB    64
#define NSPLIT 64
#define LN_EPS   1e-5f
#define ATTN_EPS 1e-8f
#define SCALE    0.125f      // 64^-0.5

typedef __bf16 bf16x8 __attribute__((ext_vector_type(8)));
typedef float  f32x4  __attribute__((ext_vector_type(4)));

// ---------------------------------------------------------------------------
// Kernel 0: pre-gather Wk|Wv into MFMA fragment order (A-operand for the
// swapped mfma(W,X) call): WTf[(ks*8+nt)*64 + lane] holds 8 bf16 =
// W[k = ks*32+(lane>>4)*8+j][col = nt*16+(lane&15)]  (col<64 -> Wk, else Wv).
// ---------------------------------------------------------------------------
__global__ void k_prep(const float* __restrict__ Wk, const float* __restrict__ Wv,
                       __bf16* __restrict__ WTf) {
  const int t = blockIdx.x * 256 + threadIdx.x;   // 0..2047
  const int fid = t >> 6, lane = t & 63;          // fid = ks*8+nt
  const int ks = fid >> 3, nt = fid & 7;
  const int col = nt * 16 + (lane & 15);
  const int kb  = ks * 32 + (lane >> 4) * 8;
  union { uint4 u; __bf16 h[8]; } o;
#pragma unroll
  for (int j = 0; j < 8; ++j) {
    const int k = kb + j;
    const float v = (col < 64) ? Wk[k * 64 + col] : Wv[k * 64 + (col - 64)];
    o.h[j] = (__bf16)v;
  }
  *((uint4*)WTf + t) = o.u;
}

// ---------------------------------------------------------------------------
// Kernel 1: fused LayerNorm(inputs) + bf16 MFMA projection -> kv[token][128]
// (cols 0..63 keys, 64..127 vals). mfma(W_frag, X_frag) -> C[c][token]:
// lane = token (lane&15), regs = 4 consecutive cols -> one 8B store per tile.
// ---------------------------------------------------------------------------
__launch_bounds__(256)
__global__ void k_lnproj(const float* __restrict__ inp, const float* __restrict__ g,
                         const float* __restrict__ bb, const __bf16* __restrict__ WTf,
                         __bf16* __restrict__ kv) {
  __shared__ __bf16 Xs[4][16][136];   // pad 8 bf16 -> row stride 272B
  const int tid = threadIdx.x, wave = tid >> 6, lane = tid & 63;
  const int half = lane >> 5, hl = lane & 31;
  const int rbase = blockIdx.x * 64 + wave * 16;

  const float4 gv = *(const float4*)(g + hl * 4);
  const float4 bv = *(const float4*)(bb + hl * 4);

#pragma unroll
  for (int p = 0; p < 8; ++p) {
    const int row = p * 2 + half;
    const float4 x = *(const float4*)(inp + (size_t)(rbase + row) * DIN + hl * 4);
    float s  = x.x + x.y + x.z + x.w;
    float sq = x.x * x.x + x.y * x.y + x.z * x.z + x.w * x.w;
#pragma unroll
    for (int o = 16; o > 0; o >>= 1) { s += __shfl_xor(s, o); sq += __shfl_xor(sq, o); }
    const float m = s * (1.f / 128.f);
    const float rstd = rsqrtf(sq * (1.f / 128.f) - m * m + LN_EPS);
    union { ushort4 u; __bf16 h[4]; } pk;
    pk.h[0] = (__bf16)((x.x - m) * rstd * gv.x + bv.x);
    pk.h[1] = (__bf16)((x.y - m) * rstd * gv.y + bv.y);
    pk.h[2] = (__bf16)((x.z - m) * rstd * gv.z + bv.z);
    pk.h[3] = (__bf16)((x.w - m) * rstd * gv.w + bv.w);
    *(ushort4*)&Xs[wave][row][hl * 4] = pk.u;
  }
  // No barrier: each wave reads only its own Xs slice (same-wave LDS dep).

  f32x4 acc[8] = {};
  const int tok = lane & 15, kgrp = lane >> 4;
  const bf16x8* __restrict__ Bv = (const bf16x8*)WTf;
#pragma unroll
  for (int ks = 0; ks < 4; ++ks) {
    const bf16x8 x = *(const bf16x8*)&Xs[wave][tok][ks * 32 + kgrp * 8];
#pragma unroll
    for (int nt = 0; nt < 8; ++nt) {
      const bf16x8 w = Bv[(ks * 8 + nt) * 64 + lane];
      // C[row=outcol][col=token]: out col = nt*16 + kgrp*4 + r, token = lane&15
      acc[nt] = __builtin_amdgcn_mfma_f32_16x16x32_bf16(w, x, acc[nt], 0, 0, 0);
    }
  }
#pragma unroll
  for (int nt = 0; nt < 8; ++nt) {
    union { unsigned long long u; __bf16 h[4]; } pk;
    pk.h[0] = (__bf16)acc[nt][0]; pk.h[1] = (__bf16)acc[nt][1];
    pk.h[2] = (__bf16)acc[nt][2]; pk.h[3] = (__bf16)acc[nt][3];
    *(unsigned long long*)&kv[(size_t)(rbase + tok) * 128 + nt * 16 + kgrp * 4] = pk.u;
  }
}

// ---------------------------------------------------------------------------
// Kernel 2: slots = broadcast(init_latents); q = LN_q(slots) @ Wq
// ---------------------------------------------------------------------------
__global__ void k_init(const float* __restrict__ init_lat, const float* __restrict__ qg,
                       const float* __restrict__ qb, const float* __restrict__ Wq,
                       float* __restrict__ slots, float* __restrict__ q) {
  const int b = blockIdx.x;
  const int k = threadIdx.x >> 6, c = threadIdx.x & 63;
  const float s = init_lat[k * DSL + c];
  slots[(size_t)(b * KSL + k) * DSL + c] = s;
  float sum = s, sq = s * s;
#pragma unroll
  for (int o = 32; o > 0; o >>= 1) { sum += __shfl_xor(sum, o); sq += __shfl_xor(sq, o); }
  const float m = sum * (1.f / 64.f);
  const float rstd = rsqrtf(sq * (1.f / 64.f) - m * m + LN_EPS);
  const float qn = (s - m) * rstd * qg[c] + qb[c];
  float acc = 0.f;
  for (int i = 0; i < DSL; ++i) acc += __shfl(qn, i) * Wq[i * DSL + c];
  q[(size_t)(b * KSL + k) * DSL + c] = acc;
}

// ---------------------------------------------------------------------------
// Kernel 3: attention pass. 1 wave / 64-token tile. Key row (256B kv row,
// first half) in registers; vals half staged to LDS (stride-72 bf16: writes
// spread all banks, uniform-row reads conflict-free). Softmax lane-local.
// ---------------------------------------------------------------------------
__launch_bounds__(64)
__global__ void k_attn(const __bf16* __restrict__ kv, const float* __restrict__ q,
                       float* __restrict__ Upart, float* __restrict__ Spart,
                       float* __restrict__ attn_out) {
  __shared__ __align__(16) float at[64 * 12];
  __shared__ __align__(16) __bf16 vst[64 * 72];
  const int b = blockIdx.x >> 6, sp = blockIdx.x & 63;
  const int lane = threadIdx.x;
  const float* __restrict__ qbp = q + b * (KSL * DSL);
  const size_t base = ((size_t)b * NTOK + sp * 64) * 128;

  unsigned int kw[32];
  {
    const uint4* __restrict__ kp = (const uint4*)(kv + base + (size_t)lane * 128);
#pragma unroll
    for (int i = 0; i < 8; ++i) {
      const uint4 t = kp[i];
      kw[4 * i] = t.x; kw[4 * i + 1] = t.y; kw[4 * i + 2] = t.z; kw[4 * i + 3] = t.w;
    }
#pragma unroll
    for (int i = 0; i < 8; ++i)           // stage vals half (cols 64..127)
      *(uint4*)&vst[lane * 72 + i * 8] = kp[8 + i];
  }
  float lg[KSL] = {0.f, 0.f, 0.f, 0.f, 0.f, 0.f, 0.f, 0.f, 0.f, 0.f, 0.f};
#pragma unroll
  for (int c2 = 0; c2 < 32; ++c2) {
    const float lo = __uint_as_float(kw[c2] << 16);
    const float hi = __uint_as_float(kw[c2] & 0xffff0000u);
#pragma unroll
    for (int m = 0; m < KSL; ++m)
      lg[m] = fmaf(hi, qbp[m * DSL + 2 * c2 + 1], fmaf(lo, qbp[m * DSL + 2 * c2], lg[m]));
  }
  float mx = lg[0] * SCALE;
#pragma unroll
  for (int m = 0; m < KSL; ++m) { lg[m] *= SCALE; mx = fmaxf(mx, lg[m]); }
  float e[KSL], se = 0.f;
#pragma unroll
  for (int m = 0; m < KSL; ++m) { e[m] = __expf(lg[m] - mx); se += e[m]; }
  const float inv = 1.f / se;
  float a[KSL];
#pragma unroll
  for (int m = 0; m < KSL; ++m) {
    a[m] = e[m] * inv + ATTN_EPS;
    at[lane * 12 + m] = a[m];
  }
  if (attn_out) {
    float* __restrict__ ao = attn_out + ((size_t)b * NTOK + sp * 64 + lane) * KSL;
#pragma unroll
    for (int m = 0; m < KSL; ++m) ao[m] = a[m];
  }

  float U[KSL] = {0.f, 0.f, 0.f, 0.f, 0.f, 0.f, 0.f, 0.f, 0.f, 0.f, 0.f};
#pragma unroll 8
  for (int n = 0; n < 64; ++n) {
    const float v = (float)vst[n * 72 + lane];
    const float4 a0 = *(const float4*)&at[n * 12 + 0];
    const float4 a1 = *(const float4*)&at[n * 12 + 4];
    const float4 a2 = *(const float4*)&at[n * 12 + 8];
    U[0] += a0.x * v; U[1] += a0.y * v; U[2]  += a0.z * v; U[3] += a0.w * v;
    U[4] += a1.x * v; U[5] += a1.y * v; U[6]  += a1.z * v; U[7] += a1.w * v;
    U[8] += a2.x * v; U[9] += a2.y * v; U[10] += a2.z * v;
  }
  float* __restrict__ up = Upart + (size_t)(b * NSPLIT + sp) * (KSL * DSL);
#pragma unroll
  for (int m = 0; m < KSL; ++m) up[m * DSL + lane] = U[m];
  float Sl[KSL];
#pragma unroll
  for (int m = 0; m < KSL; ++m) {
    Sl[m] = a[m];
#pragma unroll
    for (int o = 32; o > 0; o >>= 1) Sl[m] += __shfl_xor(Sl[m], o);
  }
  if (lane == 0) {
    float* __restrict__ spp = Spart + (size_t)(b * NSPLIT + sp) * KSL;
#pragma unroll
    for (int m = 0; m < KSL; ++m) spp[m] = Sl[m];
  }
}

// ---------------------------------------------------------------------------
// Kernel 4: reduce partials -> updates; GRU; LN_f + MLP residual; next q.
// Rows fully independent: wave = row, 176 blocks x 4 waves.
// ---------------------------------------------------------------------------
__launch_bounds__(256)
__global__ void k_update(const float* __restrict__ Upart, const float* __restrict__ Spart,
                         float* __restrict__ slots, const float* __restrict__ w_ih,
                         const float* __restrict__ w_hh, const float* __restrict__ b_ih,
                         const float* __restrict__ b_hh, const float* __restrict__ fg,
                         const float* __restrict__ fb, const float* __restrict__ W1,
                         const float* __restrict__ b1v, const float* __restrict__ W2,
                         const float* __restrict__ b2v, const float* __restrict__ qg,
                         const float* __restrict__ qbv, const float* __restrict__ Wq,
                         float* __restrict__ q, float* __restrict__ out_slots) {
  const int row = blockIdx.x * 4 + (threadIdx.x >> 6);   // 0..703
  const int c = threadIdx.x & 63;
  const int b = row / 11, k = row - b * 11;

  float u = 0.f;
  for (int s = 0; s < NSPLIT; ++s)
    u += Upart[((size_t)(b * NSPLIT + s) * KSL + k) * DSL + c];
  float ss = 0.f;
  for (int s = 0; s < NSPLIT; ++s)
    ss += Spart[(size_t)(b * NSPLIT + s) * KSL + k];
  u /= ss;

  const float h = slots[(size_t)row * DSL + c];

  float gr = b_ih[c], gz = b_ih[64 + c], gn = b_ih[128 + c];
  float hr = b_hh[c], hz = b_hh[64 + c], hn = b_hh[128 + c];
  for (int i = 0; i < 64; ++i) {
    const float ui = __shfl(u, i), hi = __shfl(h, i);
    gr += ui * w_ih[i * 192 + c];       hr += hi * w_hh[i * 192 + c];
    gz += ui * w_ih[i * 192 + 64 + c];  hz += hi * w_hh[i * 192 + 64 + c];
    gn += ui * w_ih[i * 192 + 128 + c]; hn += hi * w_hh[i * 192 + 128 + c];
  }
  const float r = 1.f / (1.f + __expf(-(gr + hr)));
  const float z = 1.f / (1.f + __expf(-(gz + hz)));
  const float nn = tanhf(gn + r * hn);
  float sv = (1.f - z) * nn + z * h;

  float sum = sv, sq = sv * sv;
#pragma unroll
  for (int o = 32; o > 0; o >>= 1) { sum += __shfl_xor(sum, o); sq += __shfl_xor(sq, o); }
  float m = sum * (1.f / 64.f);
  float rstd = rsqrtf(sq * (1.f / 64.f) - m * m + LN_EPS);
  const float sl = (sv - m) * rstd * fg[c] + fb[c];

  float h0 = b1v[c], h1 = b1v[64 + c], h2 = b1v[128 + c], h3 = b1v[192 + c];
  for (int i = 0; i < 64; ++i) {
    const float si = __shfl(sl, i);
    h0 += si * W1[i * 256 + c];        h1 += si * W1[i * 256 + 64 + c];
    h2 += si * W1[i * 256 + 128 + c];  h3 += si * W1[i * 256 + 192 + c];
  }
  h0 = fmaxf(h0, 0.f); h1 = fmaxf(h1, 0.f); h2 = fmaxf(h2, 0.f); h3 = fmaxf(h3, 0.f);

  float o = b2v[c];
  for (int j = 0; j < 64; ++j) o += __shfl(h0, j) * W2[j * DSL + c];
  for (int j = 0; j < 64; ++j) o += __shfl(h1, j) * W2[(64 + j) * DSL + c];
  for (int j = 0; j < 64; ++j) o += __shfl(h2, j) * W2[(128 + j) * DSL + c];
  for (int j = 0; j < 64; ++j) o += __shfl(h3, j) * W2[(192 + j) * DSL + c];
  sv += o;

  slots[(size_t)row * DSL + c] = sv;
  if (out_slots) out_slots[(size_t)row * DSL + c] = sv;

  float s2 = sv, q2 = sv * sv;
#pragma unroll
  for (int o2 = 32; o2 > 0; o2 >>= 1) { s2 += __shfl_xor(s2, o2); q2 += __shfl_xor(q2, o2); }
  m = s2 * (1.f / 64.f);
  rstd = rsqrtf(q2 * (1.f / 64.f) - m * m + LN_EPS);
  const float qn = (sv - m) * rstd * qg[c] + qbv[c];
  float qa = 0.f;
  for (int i = 0; i < 64; ++i) qa += __shfl(qn, i) * Wq[i * DSL + c];
  q[(size_t)row * DSL + c] = qa;
}

// ---------------------------------------------------------------------------
extern "C" void kernel_launch(void* const* d_in, const int* in_sizes, int n_in,
                              void* d_out, int out_size, void* d_ws, size_t ws_size,
                              hipStream_t stream) {
  const float* inp  = (const float*)d_in[0];
  const float* lng  = (const float*)d_in[1];
  const float* lnb  = (const float*)d_in[2];
  const float* Wk   = (const float*)d_in[3];
  const float* Wv   = (const float*)d_in[4];
  const float* init = (const float*)d_in[5];
  const float* qg   = (const float*)d_in[6];
  const float* qbb  = (const float*)d_in[7];
  const float* Wq   = (const float*)d_in[8];
  const float* wih  = (const float*)d_in[9];
  const float* whh  = (const float*)d_in[10];
  const float* bih  = (const float*)d_in[11];
  const float* bhh  = (const float*)d_in[12];
  const float* fg   = (const float*)d_in[13];
  const float* fb   = (const float*)d_in[14];
  const float* W1   = (const float*)d_in[15];
  const float* b1   = (const float*)d_in[16];
  const float* W2   = (const float*)d_in[17];
  const float* b2   = (const float*)d_in[18];

  char* wsb = (char*)d_ws;
  __bf16* kv  = (__bf16*)wsb;                                    // 67.1 MB
  __bf16* WTf = kv + (size_t)NB * NTOK * 128;                    // 32 KB
  float* slots = (float*)(WTf + 16384);
  float* q     = slots + NB * KSL * DSL;
  float* Upart = q + NB * KSL * DSL;
  float* Spart = Upart + (size_t)NB * NSPLIT * KSL * DSL;        // 11.5 MB

  float* out_slots = (float*)d_out;
  float* out_attn  = (float*)d_out + NB * KSL * DSL;

  k_prep<<<8, 256, 0, stream>>>(Wk, Wv, WTf);
  k_lnproj<<<4096, 256, 0, stream>>>(inp, lng, lnb, WTf, kv);
  k_init<<<NB, KSL * 64, 0, stream>>>(init, qg, qbb, Wq, slots, q);
  for (int t = 0; t < 3; ++t) {
    k_attn<<<NB * NSPLIT, 64, 0, stream>>>(kv, q, Upart, Spart,
                                           t == 2 ? out_attn : nullptr);
    k_update<<<176, 256, 0, stream>>>(Upart, Spart, slots, wih, whh, bih, bhh,
                                      fg, fb, W1, b1, W2, b2, qg, qbb, Wq, q,
                                      t == 2 ? out_slots : nullptr);
  }
}

// Round 4
// 188.503 us; speedup vs baseline: 2.4251x; 1.1808x over previous
//
#include <hip/hip_runtime.h>

#define DIN   128
#define DSL   64
#define KSL   11
#define NTOK  4096
#define NB    64
#define NSPLIT 64
#define LN_EPS   1e-5f
#define ATTN_EPS 1e-8f
#define SCALE    0.125f      // 64^-0.5

typedef __bf16 bf16x8 __attribute__((ext_vector_type(8)));
typedef float  f32x4  __attribute__((ext_vector_type(4)));

// ---------------------------------------------------------------------------
// Kernel 0: pre-gather Wk|Wv into MFMA A-fragment order for mfma(W, X):
// WTf[(ks*8+nt)*64 + lane] holds 8 bf16 = W[k=ks*32+(lane>>4)*8+j][outcol =
// nt*16+(lane&15)]  (outcol<64 -> Wk, else Wv).
// ---------------------------------------------------------------------------
__global__ void k_prep(const float* __restrict__ Wk, const float* __restrict__ Wv,
                       __bf16* __restrict__ WTf) {
  const int t = blockIdx.x * 256 + threadIdx.x;   // 0..2047
  const int fid = t >> 6, lane = t & 63;
  const int ks = fid >> 3, nt = fid & 7;
  const int col = nt * 16 + (lane & 15);
  const int kb  = ks * 32 + (lane >> 4) * 8;
  union { uint4 u; __bf16 h[8]; } o;
#pragma unroll
  for (int j = 0; j < 8; ++j) {
    const int k = kb + j;
    const float v = (col < 64) ? Wk[k * 64 + col] : Wv[k * 64 + (col - 64)];
    o.h[j] = (__bf16)v;
  }
  *((uint4*)WTf + t) = o.u;
}

// ---------------------------------------------------------------------------
// Kernel 1: fused LayerNorm + MFMA projection.
// Outputs: keys[b*4096+tok][64] (row-major bf16), valsT[b][c][4096] (bf16,
// transposed -- feeds PV B-fragments contiguously).
// LN phase: batch 8 row-loads -> 16 independent shuffle-reduce chains.
// ---------------------------------------------------------------------------
__launch_bounds__(256)
__global__ void k_lnproj(const float* __restrict__ inp, const float* __restrict__ g,
                         const float* __restrict__ bb, const __bf16* __restrict__ WTf,
                         __bf16* __restrict__ keys, __bf16* __restrict__ valsT) {
  __shared__ __bf16 Xs[4][16][136];
  const int tid = threadIdx.x, wave = tid >> 6, lane = tid & 63;
  const int half = lane >> 5, hl = lane & 31;
  const int rbase = blockIdx.x * 64 + wave * 16;

  const float4 gv = *(const float4*)(g + hl * 4);
  const float4 bv = *(const float4*)(bb + hl * 4);

  float4 xr[8];
#pragma unroll
  for (int p = 0; p < 8; ++p)
    xr[p] = *(const float4*)(inp + (size_t)(rbase + 2 * p + half) * DIN + hl * 4);
  __builtin_amdgcn_sched_barrier(0);

  float s[8], sq[8];
#pragma unroll
  for (int p = 0; p < 8; ++p) {
    s[p]  = xr[p].x + xr[p].y + xr[p].z + xr[p].w;
    sq[p] = xr[p].x * xr[p].x + xr[p].y * xr[p].y + xr[p].z * xr[p].z + xr[p].w * xr[p].w;
  }
#pragma unroll
  for (int o = 16; o > 0; o >>= 1) {
#pragma unroll
    for (int p = 0; p < 8; ++p) { s[p] += __shfl_xor(s[p], o); sq[p] += __shfl_xor(sq[p], o); }
  }
#pragma unroll
  for (int p = 0; p < 8; ++p) {
    const float m = s[p] * (1.f / 128.f);
    const float rstd = rsqrtf(sq[p] * (1.f / 128.f) - m * m + LN_EPS);
    union { ushort4 u; __bf16 h[4]; } pk;
    pk.h[0] = (__bf16)((xr[p].x - m) * rstd * gv.x + bv.x);
    pk.h[1] = (__bf16)((xr[p].y - m) * rstd * gv.y + bv.y);
    pk.h[2] = (__bf16)((xr[p].z - m) * rstd * gv.z + bv.z);
    pk.h[3] = (__bf16)((xr[p].w - m) * rstd * gv.w + bv.w);
    *(ushort4*)&Xs[wave][2 * p + half][hl * 4] = pk.u;
  }
  // No barrier: each wave reads only its own Xs slice.

  f32x4 acc[8] = {};
  const int tok = lane & 15, kgrp = lane >> 4;
  const bf16x8* __restrict__ Bv = (const bf16x8*)WTf;
#pragma unroll
  for (int ks = 0; ks < 4; ++ks) {
    const bf16x8 x = *(const bf16x8*)&Xs[wave][tok][ks * 32 + kgrp * 8];
#pragma unroll
    for (int nt = 0; nt < 8; ++nt) {
      const bf16x8 w = Bv[(ks * 8 + nt) * 64 + lane];
      acc[nt] = __builtin_amdgcn_mfma_f32_16x16x32_bf16(w, x, acc[nt], 0, 0, 0);
    }
  }
  // C layout: row(outcol) = nt*16 + kgrp*4 + r, col(token) = lane&15.
#pragma unroll
  for (int nt = 0; nt < 4; ++nt) {   // keys: packed 8B store
    union { unsigned long long u; __bf16 h[4]; } pk;
    pk.h[0] = (__bf16)acc[nt][0]; pk.h[1] = (__bf16)acc[nt][1];
    pk.h[2] = (__bf16)acc[nt][2]; pk.h[3] = (__bf16)acc[nt][3];
    *(unsigned long long*)&keys[(size_t)(rbase + tok) * 64 + nt * 16 + kgrp * 4] = pk.u;
  }
  const int bidx = rbase >> 12;
  const int tIB  = (rbase & 4095) + tok;
#pragma unroll
  for (int nt = 4; nt < 8; ++nt) {   // valsT: scatter (16-lane 32B contiguity)
#pragma unroll
    for (int r = 0; r < 4; ++r)
      valsT[((size_t)bidx * 64 + (nt - 4) * 16 + kgrp * 4 + r) * NTOK + tIB] = (__bf16)acc[nt][r];
  }
}

// ---------------------------------------------------------------------------
// Kernel 2: slots = broadcast(init_latents); q = LN_q(slots) @ Wq
// ---------------------------------------------------------------------------
__global__ void k_init(const float* __restrict__ init_lat, const float* __restrict__ qg,
                       const float* __restrict__ qb, const float* __restrict__ Wq,
                       float* __restrict__ slots, float* __restrict__ q) {
  const int b = blockIdx.x;
  const int k = threadIdx.x >> 6, c = threadIdx.x & 63;
  const float s = init_lat[k * DSL + c];
  slots[(size_t)(b * KSL + k) * DSL + c] = s;
  float sum = s, sq = s * s;
#pragma unroll
  for (int o = 32; o > 0; o >>= 1) { sum += __shfl_xor(sum, o); sq += __shfl_xor(sq, o); }
  const float m = sum * (1.f / 64.f);
  const float rstd = rsqrtf(sq * (1.f / 64.f) - m * m + LN_EPS);
  const float qn = (s - m) * rstd * qg[c] + qb[c];
  float acc = 0.f;
  for (int i = 0; i < DSL; ++i) acc += __shfl(qn, i) * Wq[i * DSL + c];
  q[(size_t)(b * KSL + k) * DSL + c] = acc;
}

// ---------------------------------------------------------------------------
// Kernel 3: attention via MFMA. 1 wave / 64 tokens. QK^T: mfma(q,k) ->
// C[slot][token]; softmax over slots (in-lane 4 + xor16/32); P -> LDS
// transpose (bf16); PV: mfma(P, valsT) -> U[slot][ch]. Split partials.
// ---------------------------------------------------------------------------
__launch_bounds__(64)
__global__ void k_attn(const __bf16* __restrict__ keys, const __bf16* __restrict__ valsT,
                       const float* __restrict__ q, float* __restrict__ Upart,
                       float* __restrict__ Spart, float* __restrict__ attn_out) {
  __shared__ __bf16 P[16][72];   // row stride 144B: 2-way max on b128 reads
  const int b = blockIdx.x >> 6, sp = blockIdx.x & 63;
  const int lane = threadIdx.x;
  const int g = lane >> 4, t = lane & 15;

  // Q fragments: slot = t (zero for t >= 11), ch = ks*32 + g*8 + j
  bf16x8 qf[2];
#pragma unroll
  for (int ks = 0; ks < 2; ++ks) {
    float4 q0 = {0.f, 0.f, 0.f, 0.f}, q1 = {0.f, 0.f, 0.f, 0.f};
    if (t < KSL) {
      const float* __restrict__ qp = q + (size_t)(b * KSL + t) * DSL + ks * 32 + g * 8;
      q0 = *(const float4*)qp; q1 = *(const float4*)(qp + 4);
    }
    qf[ks][0] = (__bf16)q0.x; qf[ks][1] = (__bf16)q0.y;
    qf[ks][2] = (__bf16)q0.z; qf[ks][3] = (__bf16)q0.w;
    qf[ks][4] = (__bf16)q1.x; qf[ks][5] = (__bf16)q1.y;
    qf[ks][6] = (__bf16)q1.z; qf[ks][7] = (__bf16)q1.w;
  }

  const __bf16* __restrict__ kbase = keys + ((size_t)b * NTOK + sp * 64) * DSL;
  float sacc[4] = {0.f, 0.f, 0.f, 0.f};

#pragma unroll
  for (int tile = 0; tile < 4; ++tile) {
    f32x4 c = {};
#pragma unroll
    for (int ks = 0; ks < 2; ++ks) {
      const bf16x8 kf = *(const bf16x8*)(kbase + (size_t)(tile * 16 + t) * DSL + ks * 32 + g * 8);
      c = __builtin_amdgcn_mfma_f32_16x16x32_bf16(qf[ks], kf, c, 0, 0, 0);
    }
    // lane (g,t): slots 4g+r for token tile*16+t
    float lg[4];
#pragma unroll
    for (int r = 0; r < 4; ++r)
      lg[r] = (4 * g + r < KSL) ? c[r] * SCALE : -1e30f;
    float mx = fmaxf(fmaxf(lg[0], lg[1]), fmaxf(lg[2], lg[3]));
    mx = fmaxf(mx, __shfl_xor(mx, 16));
    mx = fmaxf(mx, __shfl_xor(mx, 32));
    float e[4];
#pragma unroll
    for (int r = 0; r < 4; ++r) e[r] = __expf(lg[r] - mx);
    float se = e[0] + e[1] + e[2] + e[3];
    se += __shfl_xor(se, 16);
    se += __shfl_xor(se, 32);
    const float inv = 1.f / se;
#pragma unroll
    for (int r = 0; r < 4; ++r) {
      const float a = e[r] * inv + ATTN_EPS;
      sacc[r] += a;
      P[4 * g + r][tile * 16 + t] = (__bf16)a;
      if (attn_out && 4 * g + r < KSL)
        attn_out[((size_t)b * NTOK + sp * 64 + tile * 16 + t) * KSL + 4 * g + r] = a;
    }
  }

  // PV: A = P[slot][token] (LDS), B = valsT[c][token] (global, contiguous)
  f32x4 U[4] = {};
#pragma unroll
  for (int ks = 0; ks < 2; ++ks) {
    const bf16x8 pf = *(const bf16x8*)&P[t][ks * 32 + g * 8];
#pragma unroll
    for (int ct = 0; ct < 4; ++ct) {
      const bf16x8 vf = *(const bf16x8*)(valsT + ((size_t)b * DSL + ct * 16 + t) * NTOK
                                         + sp * 64 + ks * 32 + g * 8);
      U[ct] = __builtin_amdgcn_mfma_f32_16x16x32_bf16(pf, vf, U[ct], 0, 0, 0);
    }
  }
  // U layout: row(slot) = 4g+r, col(ch) = ct*16 + t
  float* __restrict__ up = Upart + (size_t)(b * NSPLIT + sp) * (KSL * DSL);
#pragma unroll
  for (int ct = 0; ct < 4; ++ct)
#pragma unroll
    for (int r = 0; r < 4; ++r)
      if (4 * g + r < KSL) up[(4 * g + r) * DSL + ct * 16 + t] = U[ct][r];

#pragma unroll
  for (int r = 0; r < 4; ++r) {
#pragma unroll
    for (int o = 1; o < 16; o <<= 1) sacc[r] += __shfl_xor(sacc[r], o);
  }
  if (t == 0) {
    float* __restrict__ spp = Spart + (size_t)(b * NSPLIT + sp) * 16;
#pragma unroll
    for (int r = 0; r < 4; ++r) spp[4 * g + r] = sacc[r];
  }
}

// ---------------------------------------------------------------------------
// Kernel 4: reduce partials -> updates; GRU; LN_f + MLP residual; next q.
// 704 blocks x 64 threads (wave = row).
// ---------------------------------------------------------------------------
__launch_bounds__(64)
__global__ void k_update(const float* __restrict__ Upart, const float* __restrict__ Spart,
                         float* __restrict__ slots, const float* __restrict__ w_ih,
                         const float* __restrict__ w_hh, const float* __restrict__ b_ih,
                         const float* __restrict__ b_hh, const float* __restrict__ fg,
                         const float* __restrict__ fb, const float* __restrict__ W1,
                         const float* __restrict__ b1v, const float* __restrict__ W2,
                         const float* __restrict__ b2v, const float* __restrict__ qg,
                         const float* __restrict__ qbv, const float* __restrict__ Wq,
                         float* __restrict__ q, float* __restrict__ out_slots) {
  const int row = blockIdx.x;            // 0..703
  const int c = threadIdx.x;
  const int b = row / 11, k = row - b * 11;

  float u = 0.f;
  for (int s = 0; s < NSPLIT; ++s)
    u += Upart[((size_t)(b * NSPLIT + s) * KSL + k) * DSL + c];
  float ss = 0.f;
  for (int s = 0; s < NSPLIT; ++s)
    ss += Spart[(size_t)(b * NSPLIT + s) * 16 + k];
  u /= ss;

  const float h = slots[(size_t)row * DSL + c];

  float gr = b_ih[c], gz = b_ih[64 + c], gn = b_ih[128 + c];
  float hr = b_hh[c], hz = b_hh[64 + c], hn = b_hh[128 + c];
  for (int i = 0; i < 64; ++i) {
    const float ui = __shfl(u, i), hi = __shfl(h, i);
    gr += ui * w_ih[i * 192 + c];       hr += hi * w_hh[i * 192 + c];
    gz += ui * w_ih[i * 192 + 64 + c];  hz += hi * w_hh[i * 192 + 64 + c];
    gn += ui * w_ih[i * 192 + 128 + c]; hn += hi * w_hh[i * 192 + 128 + c];
  }
  const float r = 1.f / (1.f + __expf(-(gr + hr)));
  const float z = 1.f / (1.f + __expf(-(gz + hz)));
  const float nn = tanhf(gn + r * hn);
  float sv = (1.f - z) * nn + z * h;

  float sum = sv, sq = sv * sv;
#pragma unroll
  for (int o = 32; o > 0; o >>= 1) { sum += __shfl_xor(sum, o); sq += __shfl_xor(sq, o); }
  float m = sum * (1.f / 64.f);
  float rstd = rsqrtf(sq * (1.f / 64.f) - m * m + LN_EPS);
  const float sl = (sv - m) * rstd * fg[c] + fb[c];

  float h0 = b1v[c], h1 = b1v[64 + c], h2 = b1v[128 + c], h3 = b1v[192 + c];
  for (int i = 0; i < 64; ++i) {
    const float si = __shfl(sl, i);
    h0 += si * W1[i * 256 + c];        h1 += si * W1[i * 256 + 64 + c];
    h2 += si * W1[i * 256 + 128 + c];  h3 += si * W1[i * 256 + 192 + c];
  }
  h0 = fmaxf(h0, 0.f); h1 = fmaxf(h1, 0.f); h2 = fmaxf(h2, 0.f); h3 = fmaxf(h3, 0.f);

  float o = b2v[c];
  for (int j = 0; j < 64; ++j) o += __shfl(h0, j) * W2[j * DSL + c];
  for (int j = 0; j < 64; ++j) o += __shfl(h1, j) * W2[(64 + j) * DSL + c];
  for (int j = 0; j < 64; ++j) o += __shfl(h2, j) * W2[(128 + j) * DSL + c];
  for (int j = 0; j < 64; ++j) o += __shfl(h3, j) * W2[(192 + j) * DSL + c];
  sv += o;

  slots[(size_t)row * DSL + c] = sv;
  if (out_slots) out_slots[(size_t)row * DSL + c] = sv;

  float s2 = sv, q2 = sv * sv;
#pragma unroll
  for (int o2 = 32; o2 > 0; o2 >>= 1) { s2 += __shfl_xor(s2, o2); q2 += __shfl_xor(q2, o2); }
  m = s2 * (1.f / 64.f);
  rstd = rsqrtf(q2 * (1.f / 64.f) - m * m + LN_EPS);
  const float qn = (sv - m) * rstd * qg[c] + qbv[c];
  float qa = 0.f;
  for (int i = 0; i < 64; ++i) qa += __shfl(qn, i) * Wq[i * DSL + c];
  q[(size_t)row * DSL + c] = qa;
}

// ---------------------------------------------------------------------------
extern "C" void kernel_launch(void* const* d_in, const int* in_sizes, int n_in,
                              void* d_out, int out_size, void* d_ws, size_t ws_size,
                              hipStream_t stream) {
  const float* inp  = (const float*)d_in[0];
  const float* lng  = (const float*)d_in[1];
  const float* lnb  = (const float*)d_in[2];
  const float* Wk   = (const float*)d_in[3];
  const float* Wv   = (const float*)d_in[4];
  const float* init = (const float*)d_in[5];
  const float* qg   = (const float*)d_in[6];
  const float* qbb  = (const float*)d_in[7];
  const float* Wq   = (const float*)d_in[8];
  const float* wih  = (const float*)d_in[9];
  const float* whh  = (const float*)d_in[10];
  const float* bih  = (const float*)d_in[11];
  const float* bhh  = (const float*)d_in[12];
  const float* fg   = (const float*)d_in[13];
  const float* fb   = (const float*)d_in[14];
  const float* W1   = (const float*)d_in[15];
  const float* b1   = (const float*)d_in[16];
  const float* W2   = (const float*)d_in[17];
  const float* b2   = (const float*)d_in[18];

  char* wsb = (char*)d_ws;
  __bf16* keys  = (__bf16*)wsb;                                  // 33.55 MB
  __bf16* valsT = keys + (size_t)NB * NTOK * DSL;                // 33.55 MB
  __bf16* WTf   = valsT + (size_t)NB * DSL * NTOK;               // 32 KB
  float* slots = (float*)(WTf + 16384);
  float* q     = slots + NB * KSL * DSL;
  float* Upart = q + NB * KSL * DSL;                             // 11.5 MB
  float* Spart = Upart + (size_t)NB * NSPLIT * KSL * DSL;        // 256 KB

  float* out_slots = (float*)d_out;
  float* out_attn  = (float*)d_out + NB * KSL * DSL;

  k_prep<<<8, 256, 0, stream>>>(Wk, Wv, WTf);
  k_lnproj<<<4096, 256, 0, stream>>>(inp, lng, lnb, WTf, keys, valsT);
  k_init<<<NB, KSL * 64, 0, stream>>>(init, qg, qbb, Wq, slots, q);
  for (int t = 0; t < 3; ++t) {
    k_attn<<<NB * NSPLIT, 64, 0, stream>>>(keys, valsT, q, Upart, Spart,
                                           t == 2 ? out_attn : nullptr);
    k_update<<<NB * KSL, 64, 0, stream>>>(Upart, Spart, slots, wih, whh, bih, bhh,
                                          fg, fb, W1, b1, W2, b2, qg, qbb, Wq, q,
                                          t == 2 ? out_slots : nullptr);
  }
}

// Round 5
// 185.229 us; speedup vs baseline: 2.4680x; 1.0177x over previous
//
#include <hip/hip_runtime.h>

#define DIN   128
#define DSL   64
#define KSL   11
#define NTOK  4096
#define NB    64
#define NSPLIT 32
#define LN_EPS   1e-5f
#define ATTN_EPS 1e-8f
#define SCALE    0.125f      // 64^-0.5

typedef __bf16 bf16x8 __attribute__((ext_vector_type(8)));
typedef float  f32x4  __attribute__((ext_vector_type(4)));

// ---------------------------------------------------------------------------
// Kernel 0 (9 blocks): blocks 0..7 pre-gather W' = diag(g)·[Wk|Wv] into MFMA
// A-fragment order: WTf[(ks*8+nt)*64+lane] = 8 bf16 of
// W'[k=ks*32+(lane>>4)*8+j][outcol=nt*16+(lane&15)].
// Block 8 (first 128 lanes): EP[c] = G[c] = sum_k g[k]·W[k][c],
// EP[128+c] = Bt[c] = sum_k b[k]·W[k][c].
// ---------------------------------------------------------------------------
__global__ void k_prep(const float* __restrict__ Wk, const float* __restrict__ Wv,
                       const float* __restrict__ g, const float* __restrict__ b,
                       __bf16* __restrict__ WTf, float* __restrict__ EP) {
  if (blockIdx.x == 8) {
    const int c = threadIdx.x;
    if (c < 128) {
      const float* __restrict__ W = (c < 64) ? Wk : Wv;
      const int cc = c & 63;
      float G = 0.f, Bt = 0.f;
      for (int k = 0; k < 128; ++k) {
        const float w = W[k * 64 + cc];
        G += g[k] * w; Bt += b[k] * w;
      }
      EP[c] = G; EP[128 + c] = Bt;
    }
    return;
  }
  const int t = blockIdx.x * 256 + threadIdx.x;   // 0..2047
  const int fid = t >> 6, lane = t & 63;
  const int ks = fid >> 3, nt = fid & 7;
  const int col = nt * 16 + (lane & 15);
  const int kb  = ks * 32 + (lane >> 4) * 8;
  union { uint4 u; __bf16 h[8]; } o;
#pragma unroll
  for (int j = 0; j < 8; ++j) {
    const int k = kb + j;
    const float v = ((col < 64) ? Wk[k * 64 + col] : Wv[k * 64 + (col - 64)]) * g[k];
    o.h[j] = (__bf16)v;
  }
  *((uint4*)WTf + t) = o.u;
}

// ---------------------------------------------------------------------------
// Kernel 1: raw-x bf16 MFMA projection with LN folded into the epilogue:
// out = rstd·(x@W') − (rstd·m)·G + Bt.  The shuffle-reduce (m, rstd) runs
// concurrently with the MFMA chain; W-frags prefetched one ks ahead.
// ---------------------------------------------------------------------------
__launch_bounds__(256)
__global__ void k_lnproj(const float* __restrict__ inp, const __bf16* __restrict__ WTf,
                         const float* __restrict__ EP, __bf16* __restrict__ keys,
                         __bf16* __restrict__ valsT) {
  __shared__ __bf16 Xs[4][16][136];
  __shared__ float rowstats[4][16][2];
  const int tid = threadIdx.x, wave = tid >> 6, lane = tid & 63;
  const int half = lane >> 5, hl = lane & 31;
  const int t = lane & 15, g = lane >> 4;
  const int rbase = blockIdx.x * 64 + wave * 16;

  // 1. batch row loads
  float4 xr[8];
#pragma unroll
  for (int p = 0; p < 8; ++p)
    xr[p] = *(const float4*)(inp + (size_t)(rbase + 2 * p + half) * DIN + hl * 4);

  // 2. raw-x -> bf16 -> LDS transpose (no dependence on stats)
  float s[8], sq[8];
#pragma unroll
  for (int p = 0; p < 8; ++p) {
    s[p]  = xr[p].x + xr[p].y + xr[p].z + xr[p].w;
    sq[p] = xr[p].x * xr[p].x + xr[p].y * xr[p].y + xr[p].z * xr[p].z + xr[p].w * xr[p].w;
    union { ushort4 u; __bf16 h[4]; } pk;
    pk.h[0] = (__bf16)xr[p].x; pk.h[1] = (__bf16)xr[p].y;
    pk.h[2] = (__bf16)xr[p].z; pk.h[3] = (__bf16)xr[p].w;
    *(ushort4*)&Xs[wave][2 * p + half][hl * 4] = pk.u;
  }

  // 3. stats reduce (DS pipe, concurrent with MFMA below per-wave scheduling)
#pragma unroll
  for (int o = 16; o > 0; o >>= 1) {
#pragma unroll
    for (int p = 0; p < 8; ++p) { s[p] += __shfl_xor(s[p], o); sq[p] += __shfl_xor(sq[p], o); }
  }
  if (hl < 8) {
    const int p = hl;
    const float m = s[p] * (1.f / 128.f);
    const float rstd = rsqrtf(sq[p] * (1.f / 128.f) - m * m + LN_EPS);
    rowstats[wave][2 * p + half][0] = m;
    rowstats[wave][2 * p + half][1] = rstd;
  }

  // 4. MFMA with W-frag prefetch (A = W' frag, B = raw-x frag)
  const bf16x8* __restrict__ Wv8 = (const bf16x8*)WTf;
  bf16x8 wf[8];
#pragma unroll
  for (int nt = 0; nt < 8; ++nt) wf[nt] = Wv8[nt * 64 + lane];
  f32x4 acc[8] = {};
#pragma unroll
  for (int ks = 0; ks < 4; ++ks) {
    const bf16x8 xf = *(const bf16x8*)&Xs[wave][t][ks * 32 + g * 8];
    bf16x8 wn[8];
    if (ks < 3) {
#pragma unroll
      for (int nt = 0; nt < 8; ++nt) wn[nt] = Wv8[((ks + 1) * 8 + nt) * 64 + lane];
    }
#pragma unroll
    for (int nt = 0; nt < 8; ++nt)
      acc[nt] = __builtin_amdgcn_mfma_f32_16x16x32_bf16(wf[nt], xf, acc[nt], 0, 0, 0);
#pragma unroll
    for (int nt = 0; nt < 8; ++nt) wf[nt] = wn[nt];
  }

  // 5. epilogue: LN applied to accumulators. C row = outcol(nt*16+g*4+r), col = t.
  const float2 mrs = *(const float2*)&rowstats[wave][t][0];
  const float rstd = mrs.y, mm = mrs.x * mrs.y;
  const int bidx = rbase >> 12;
  const int tIB  = (rbase & 4095) + t;
#pragma unroll
  for (int nt = 0; nt < 8; ++nt) {
    const float4 Gv = *(const float4*)(EP + nt * 16 + g * 4);
    const float4 Bv = *(const float4*)(EP + 128 + nt * 16 + g * 4);
    float o0 = rstd * acc[nt][0] - mm * Gv.x + Bv.x;
    float o1 = rstd * acc[nt][1] - mm * Gv.y + Bv.y;
    float o2 = rstd * acc[nt][2] - mm * Gv.z + Bv.z;
    float o3 = rstd * acc[nt][3] - mm * Gv.w + Bv.w;
    if (nt < 4) {
      union { unsigned long long u; __bf16 h[4]; } pk;
      pk.h[0] = (__bf16)o0; pk.h[1] = (__bf16)o1; pk.h[2] = (__bf16)o2; pk.h[3] = (__bf16)o3;
      *(unsigned long long*)&keys[(size_t)(rbase + t) * 64 + nt * 16 + g * 4] = pk.u;
    } else {
      const int vc = (nt - 4) * 16 + g * 4;
      valsT[((size_t)bidx * 64 + vc + 0) * NTOK + tIB] = (__bf16)o0;
      valsT[((size_t)bidx * 64 + vc + 1) * NTOK + tIB] = (__bf16)o1;
      valsT[((size_t)bidx * 64 + vc + 2) * NTOK + tIB] = (__bf16)o2;
      valsT[((size_t)bidx * 64 + vc + 3) * NTOK + tIB] = (__bf16)o3;
    }
  }
}

// ---------------------------------------------------------------------------
// Kernel 2: slots = broadcast(init_latents); q = SCALE·(LN_q(slots) @ Wq)
// ---------------------------------------------------------------------------
__global__ void k_init(const float* __restrict__ init_lat, const float* __restrict__ qg,
                       const float* __restrict__ qb, const float* __restrict__ Wq,
                       float* __restrict__ slots, float* __restrict__ q) {
  const int b = blockIdx.x;
  const int k = threadIdx.x >> 6, c = threadIdx.x & 63;
  const float s = init_lat[k * DSL + c];
  slots[(size_t)(b * KSL + k) * DSL + c] = s;
  float sum = s, sq = s * s;
#pragma unroll
  for (int o = 32; o > 0; o >>= 1) { sum += __shfl_xor(sum, o); sq += __shfl_xor(sq, o); }
  const float m = sum * (1.f / 64.f);
  const float rstd = rsqrtf(sq * (1.f / 64.f) - m * m + LN_EPS);
  const float qn = (s - m) * rstd * qg[c] + qb[c];
  float acc = 0.f;
  for (int i = 0; i < DSL; ++i) acc += __shfl(qn, i) * Wq[i * DSL + c];
  q[(size_t)(b * KSL + k) * DSL + c] = acc * SCALE;
}

// ---------------------------------------------------------------------------
// Kernel 3: attention via MFMA. 1 wave / 128 tokens (2 groups of 64).
// QK^T: mfma(q,k) -> C[slot][token]; softmax over slots; P -> LDS; PV:
// mfma(P, valsT). Deterministic split partials (NSPLIT=32).
// ---------------------------------------------------------------------------
__launch_bounds__(64)
__global__ void k_attn(const __bf16* __restrict__ keys, const __bf16* __restrict__ valsT,
                       const float* __restrict__ q, float* __restrict__ Upart,
                       float* __restrict__ Spart, float* __restrict__ attn_out) {
  __shared__ __bf16 P[2][16][72];
  const int b = blockIdx.x >> 5, sp = blockIdx.x & 31;
  const int lane = threadIdx.x;
  const int g = lane >> 4, t = lane & 15;

  bf16x8 qf[2];
#pragma unroll
  for (int ks = 0; ks < 2; ++ks) {
    float4 q0 = {0.f, 0.f, 0.f, 0.f}, q1 = {0.f, 0.f, 0.f, 0.f};
    if (t < KSL) {
      const float* __restrict__ qp = q + (size_t)(b * KSL + t) * DSL + ks * 32 + g * 8;
      q0 = *(const float4*)qp; q1 = *(const float4*)(qp + 4);
    }
    qf[ks][0] = (__bf16)q0.x; qf[ks][1] = (__bf16)q0.y;
    qf[ks][2] = (__bf16)q0.z; qf[ks][3] = (__bf16)q0.w;
    qf[ks][4] = (__bf16)q1.x; qf[ks][5] = (__bf16)q1.y;
    qf[ks][6] = (__bf16)q1.z; qf[ks][7] = (__bf16)q1.w;
  }

  const __bf16* __restrict__ kbase = keys + ((size_t)b * NTOK + sp * 128) * DSL;
  float sacc[4] = {0.f, 0.f, 0.f, 0.f};
  f32x4 U[4] = {};

#pragma unroll
  for (int gr = 0; gr < 2; ++gr) {
    const int tb = gr * 64;
#pragma unroll
    for (int tile = 0; tile < 4; ++tile) {
      f32x4 c = {};
#pragma unroll
      for (int ks = 0; ks < 2; ++ks) {
        const bf16x8 kf = *(const bf16x8*)(kbase + (size_t)(tb + tile * 16 + t) * DSL
                                           + ks * 32 + g * 8);
        c = __builtin_amdgcn_mfma_f32_16x16x32_bf16(qf[ks], kf, c, 0, 0, 0);
      }
      float lg[4];
#pragma unroll
      for (int r = 0; r < 4; ++r)
        lg[r] = (4 * g + r < KSL) ? c[r] : -1e30f;   // q pre-scaled
      float mx = fmaxf(fmaxf(lg[0], lg[1]), fmaxf(lg[2], lg[3]));
      mx = fmaxf(mx, __shfl_xor(mx, 16));
      mx = fmaxf(mx, __shfl_xor(mx, 32));
      float e[4];
#pragma unroll
      for (int r = 0; r < 4; ++r) e[r] = __expf(lg[r] - mx);
      float se = e[0] + e[1] + e[2] + e[3];
      se += __shfl_xor(se, 16);
      se += __shfl_xor(se, 32);
      const float inv = 1.f / se;
#pragma unroll
      for (int r = 0; r < 4; ++r) {
        const float a = e[r] * inv + ATTN_EPS;
        sacc[r] += a;
        P[gr][4 * g + r][tile * 16 + t] = (__bf16)a;
        if (attn_out && 4 * g + r < KSL)
          attn_out[((size_t)b * NTOK + sp * 128 + tb + tile * 16 + t) * KSL + 4 * g + r] = a;
      }
    }
#pragma unroll
    for (int ks = 0; ks < 2; ++ks) {
      const bf16x8 pf = *(const bf16x8*)&P[gr][t][ks * 32 + g * 8];
#pragma unroll
      for (int ct = 0; ct < 4; ++ct) {
        const bf16x8 vf = *(const bf16x8*)(valsT + ((size_t)b * DSL + ct * 16 + t) * NTOK
                                           + sp * 128 + tb + ks * 32 + g * 8);
        U[ct] = __builtin_amdgcn_mfma_f32_16x16x32_bf16(pf, vf, U[ct], 0, 0, 0);
      }
    }
  }

  float* __restrict__ up = Upart + (size_t)(b * NSPLIT + sp) * (KSL * DSL);
#pragma unroll
  for (int ct = 0; ct < 4; ++ct)
#pragma unroll
    for (int r = 0; r < 4; ++r)
      if (4 * g + r < KSL) up[(4 * g + r) * DSL + ct * 16 + t] = U[ct][r];

#pragma unroll
  for (int r = 0; r < 4; ++r) {
#pragma unroll
    for (int o = 1; o < 16; o <<= 1) sacc[r] += __shfl_xor(sacc[r], o);
  }
  if (t == 0) {
    float* __restrict__ spp = Spart + (size_t)(b * NSPLIT + sp) * 16;
#pragma unroll
    for (int r = 0; r < 4; ++r) spp[4 * g + r] = sacc[r];
  }
}

// ---------------------------------------------------------------------------
// Kernel 4: reduce partials -> updates; GRU; LN_f + MLP residual; next q.
// ---------------------------------------------------------------------------
__launch_bounds__(64)
__global__ void k_update(const float* __restrict__ Upart, const float* __restrict__ Spart,
                         float* __restrict__ slots, const float* __restrict__ w_ih,
                         const float* __restrict__ w_hh, const float* __restrict__ b_ih,
                         const float* __restrict__ b_hh, const float* __restrict__ fg,
                         const float* __restrict__ fb, const float* __restrict__ W1,
                         const float* __restrict__ b1v, const float* __restrict__ W2,
                         const float* __restrict__ b2v, const float* __restrict__ qg,
                         const float* __restrict__ qbv, const float* __restrict__ Wq,
                         float* __restrict__ q, float* __restrict__ out_slots) {
  const int row = blockIdx.x;            // 0..703
  const int c = threadIdx.x;
  const int b = row / 11, k = row - b * 11;

  float u = 0.f;
  for (int s = 0; s < NSPLIT; ++s)
    u += Upart[((size_t)(b * NSPLIT + s) * KSL + k) * DSL + c];
  float ss = 0.f;
  for (int s = 0; s < NSPLIT; ++s)
    ss += Spart[(size_t)(b * NSPLIT + s) * 16 + k];
  u /= ss;

  const float h = slots[(size_t)row * DSL + c];

  float gr = b_ih[c], gz = b_ih[64 + c], gn = b_ih[128 + c];
  float hr = b_hh[c], hz = b_hh[64 + c], hn = b_hh[128 + c];
  for (int i = 0; i < 64; ++i) {
    const float ui = __shfl(u, i), hi = __shfl(h, i);
    gr += ui * w_ih[i * 192 + c];       hr += hi * w_hh[i * 192 + c];
    gz += ui * w_ih[i * 192 + 64 + c];  hz += hi * w_hh[i * 192 + 64 + c];
    gn += ui * w_ih[i * 192 + 128 + c]; hn += hi * w_hh[i * 192 + 128 + c];
  }
  const float r = 1.f / (1.f + __expf(-(gr + hr)));
  const float z = 1.f / (1.f + __expf(-(gz + hz)));
  const float nn = tanhf(gn + r * hn);
  float sv = (1.f - z) * nn + z * h;

  float sum = sv, sq = sv * sv;
#pragma unroll
  for (int o = 32; o > 0; o >>= 1) { sum += __shfl_xor(sum, o); sq += __shfl_xor(sq, o); }
  float m = sum * (1.f / 64.f);
  float rstd = rsqrtf(sq * (1.f / 64.f) - m * m + LN_EPS);
  const float sl = (sv - m) * rstd * fg[c] + fb[c];

  float h0 = b1v[c], h1 = b1v[64 + c], h2 = b1v[128 + c], h3 = b1v[192 + c];
  for (int i = 0; i < 64; ++i) {
    const float si = __shfl(sl, i);
    h0 += si * W1[i * 256 + c];        h1 += si * W1[i * 256 + 64 + c];
    h2 += si * W1[i * 256 + 128 + c];  h3 += si * W1[i * 256 + 192 + c];
  }
  h0 = fmaxf(h0, 0.f); h1 = fmaxf(h1, 0.f); h2 = fmaxf(h2, 0.f); h3 = fmaxf(h3, 0.f);

  float o = b2v[c];
  for (int j = 0; j < 64; ++j) o += __shfl(h0, j) * W2[j * DSL + c];
  for (int j = 0; j < 64; ++j) o += __shfl(h1, j) * W2[(64 + j) * DSL + c];
  for (int j = 0; j < 64; ++j) o += __shfl(h2, j) * W2[(128 + j) * DSL + c];
  for (int j = 0; j < 64; ++j) o += __shfl(h3, j) * W2[(192 + j) * DSL + c];
  sv += o;

  slots[(size_t)row * DSL + c] = sv;
  if (out_slots) out_slots[(size_t)row * DSL + c] = sv;

  float s2 = sv, q2 = sv * sv;
#pragma unroll
  for (int o2 = 32; o2 > 0; o2 >>= 1) { s2 += __shfl_xor(s2, o2); q2 += __shfl_xor(q2, o2); }
  m = s2 * (1.f / 64.f);
  rstd = rsqrtf(q2 * (1.f / 64.f) - m * m + LN_EPS);
  const float qn = (sv - m) * rstd * qg[c] + qbv[c];
  float qa = 0.f;
  for (int i = 0; i < 64; ++i) qa += __shfl(qn, i) * Wq[i * DSL + c];
  q[(size_t)row * DSL + c] = qa * SCALE;
}

// ---------------------------------------------------------------------------
extern "C" void kernel_launch(void* const* d_in, const int* in_sizes, int n_in,
                              void* d_out, int out_size, void* d_ws, size_t ws_size,
                              hipStream_t stream) {
  const float* inp  = (const float*)d_in[0];
  const float* lng  = (const float*)d_in[1];
  const float* lnb  = (const float*)d_in[2];
  const float* Wk   = (const float*)d_in[3];
  const float* Wv   = (const float*)d_in[4];
  const float* init = (const float*)d_in[5];
  const float* qg   = (const float*)d_in[6];
  const float* qbb  = (const float*)d_in[7];
  const float* Wq   = (const float*)d_in[8];
  const float* wih  = (const float*)d_in[9];
  const float* whh  = (const float*)d_in[10];
  const float* bih  = (const float*)d_in[11];
  const float* bhh  = (const float*)d_in[12];
  const float* fg   = (const float*)d_in[13];
  const float* fb   = (const float*)d_in[14];
  const float* W1   = (const float*)d_in[15];
  const float* b1   = (const float*)d_in[16];
  const float* W2   = (const float*)d_in[17];
  const float* b2   = (const float*)d_in[18];

  char* wsb = (char*)d_ws;
  __bf16* keys  = (__bf16*)wsb;                                  // 33.55 MB
  __bf16* valsT = keys + (size_t)NB * NTOK * DSL;                // 33.55 MB
  __bf16* WTf   = valsT + (size_t)NB * DSL * NTOK;               // 32 KB
  float* EP    = (float*)(WTf + 16384);                          // 1 KB
  float* slots = EP + 256;
  float* q     = slots + NB * KSL * DSL;
  float* Upart = q + NB * KSL * DSL;                             // 5.77 MB
  float* Spart = Upart + (size_t)NB * NSPLIT * KSL * DSL;        // 128 KB

  float* out_slots = (float*)d_out;
  float* out_attn  = (float*)d_out + NB * KSL * DSL;

  k_prep<<<9, 256, 0, stream>>>(Wk, Wv, lng, lnb, WTf, EP);
  k_lnproj<<<4096, 256, 0, stream>>>(inp, WTf, EP, keys, valsT);
  k_init<<<NB, KSL * 64, 0, stream>>>(init, qg, qbb, Wq, slots, q);
  for (int t = 0; t < 3; ++t) {
    k_attn<<<NB * NSPLIT, 64, 0, stream>>>(keys, valsT, q, Upart, Spart,
                                           t == 2 ? out_attn : nullptr);
    k_update<<<NB * KSL, 64, 0, stream>>>(Upart, Spart, slots, wih, whh, bih, bhh,
                                          fg, fb, W1, b1, W2, b2, qg, qbb, Wq, q,
                                          t == 2 ? out_slots : nullptr);
  }
}